// Round 1
// baseline (397.764 us; speedup 1.0000x reference)
//
#include <hip/hip_runtime.h>

// Link_Embedding: out[e] = concat(X[src[e]], X[dst[e]])
// X: 100000 x 128 fp32, indices: 320000 x 2 (int32 per harness), out: 320000 x 256 fp32.
// Pure memory-bound gather; one thread per float4 of output.

#define N_EDGES 320000
#define D_FEAT  128           // floats per row
#define F4_PER_ROW 32         // float4 per input row
#define F4_PER_OUT 64         // float4 per output row (2 rows concatenated)

__global__ __launch_bounds__(256) void link_embed_gather(
    const float4* __restrict__ X,    // N_NODES x 32 float4
    const int*    __restrict__ idx,  // N_EDGES x 2 (src, dst interleaved)
    float4*       __restrict__ out)  // N_EDGES x 64 float4
{
    const long long total = (long long)N_EDGES * F4_PER_OUT;  // 20,480,000
    long long i = (long long)blockIdx.x * blockDim.x + threadIdx.x;
    const long long stride = (long long)gridDim.x * blockDim.x;
    for (; i < total; i += stride) {
        const int e     = (int)(i >> 6);      // edge id
        const int j     = (int)(i & 63);      // float4 col within output row
        const int which = j >> 5;             // 0 = src half, 1 = dst half
        const int col   = j & 31;             // float4 col within input row
        const int row   = idx[2 * e + which]; // broadcast within half-wave
        out[i] = X[(long long)row * F4_PER_ROW + col];
    }
}

extern "C" void kernel_launch(void* const* d_in, const int* in_sizes, int n_in,
                              void* d_out, int out_size, void* d_ws, size_t ws_size,
                              hipStream_t stream) {
    const float4* X   = (const float4*)d_in[0];
    const int*    idx = (const int*)d_in[1];
    float4*       out = (float4*)d_out;

    const int total_f4 = N_EDGES * F4_PER_OUT;          // 20,480,000
    const int block    = 256;
    const int grid     = (total_f4 + block - 1) / block; // 80,000 blocks
    link_embed_gather<<<grid, block, 0, stream>>>(X, idx, out);
}

// Round 3
// 379.997 us; speedup vs baseline: 1.0468x; 1.0468x over previous
//
#include <hip/hip_runtime.h>

// Link_Embedding: out[e] = concat(X[src[e]], X[dst[e]])
// X: 100000 x 128 fp32 (51.2 MB), idx: 320000 x 2 int32, out: 320000 x 256 fp32 (327.7 MB).
// Memory-bound random gather + streaming write.
//
// R3 = R2 with the compile fix: __builtin_nontemporal_store requires a native
// clang vector type, not HIP's struct float4. Use ext_vector_type(4) floats.
//
// R2 changes vs R1 (398 us):
//  - UNROLL=4: each thread handles 4 output float4 slots -> 4 independent
//    idx loads then 4 independent row loads in flight (was 1). Latency hiding.
//  - Nontemporal stores: keep the 327 MB write stream from thrashing X out of
//    the 256 MiB Infinity Cache, so random row re-reads hit L3 not HBM.

typedef float f4 __attribute__((ext_vector_type(4)));

#define N_EDGES 320000
#define F4_PER_ROW 32         // float4 per input row (128 floats)
#define F4_PER_OUT 64         // float4 per output row (256 floats)
#define UNROLL 4
#define BLOCK 256

// total float4 slots = 320000*64 = 20,480,000 = 20,000 blocks * 256 threads * 4
#define GRID 20000

__global__ __launch_bounds__(BLOCK) void link_embed_gather(
    const f4* __restrict__ X,    // N_NODES x 32 f4
    const int* __restrict__ idx, // N_EDGES x 2 (src, dst interleaved)
    f4*       __restrict__ out)  // N_EDGES x 64 f4
{
    // slot for (k): blockIdx*1024 + k*256 + tid
    // Within a wave (64 lanes), for fixed k the 64 slots are consecutive:
    // exactly one edge; lanes 0-31 read the src row, lanes 32-63 the dst row.
    const long long base = (long long)blockIdx.x * (BLOCK * UNROLL) + threadIdx.x;

    long long slot[UNROLL];
    int       row[UNROLL];
    int       col[UNROLL];

    // Stage 1: all idx loads issued back-to-back (independent).
    #pragma unroll
    for (int k = 0; k < UNROLL; ++k) {
        slot[k] = base + (long long)k * BLOCK;
        const int e     = (int)(slot[k] >> 6);
        const int j     = (int)(slot[k] & 63);
        const int which = j >> 5;
        col[k]          = j & 31;
        row[k]          = idx[2 * e + which];
    }

    // Stage 2: all row loads issued back-to-back (independent, random).
    f4 v[UNROLL];
    #pragma unroll
    for (int k = 0; k < UNROLL; ++k) {
        v[k] = X[(long long)row[k] * F4_PER_ROW + col[k]];
    }

    // Stage 3: nontemporal streaming stores (coalesced 1 KB per wave per k).
    #pragma unroll
    for (int k = 0; k < UNROLL; ++k) {
        __builtin_nontemporal_store(v[k], &out[slot[k]]);
    }
}

extern "C" void kernel_launch(void* const* d_in, const int* in_sizes, int n_in,
                              void* d_out, int out_size, void* d_ws, size_t ws_size,
                              hipStream_t stream) {
    const f4*  X   = (const f4*)d_in[0];
    const int* idx = (const int*)d_in[1];
    f4*        out = (f4*)d_out;

    link_embed_gather<<<GRID, BLOCK, 0, stream>>>(X, idx, out);
}